// Round 11
// baseline (594.691 us; speedup 1.0000x reference)
//
#include <hip/hip_runtime.h>

// Problem constants (fixed by the reference)
#define NN 100000
#define NE 3200000
#define DD 16
#define NB 782              // ceil(NN / 128) coarse buckets (128 dsts each)
#define NBP 1024            // padded bucket count
#define CHUNK 8192          // edges per bucket_scatter block
#define NCHUNK ((NE + CHUNK - 1) / CHUNK)   // 391
#define BCAP2 4864          // fixed capacity per bucket (mean 4092 + 12 sigma)
#define DBK 64              // degree buckets for gather load-balancing

constexpr float LAM   = 1.0f;
constexpr float ALP   = 1.0f / (LAM + 1.0f);   // 0.5
constexpr float GAMMA = ALP * LAM;             // 0.5
// (1 - ALP - ALP*LAM) == 0 at these constants -> no Y carry term

// bf16 helpers: RTNE pack, cheap unpack
static __device__ inline unsigned short f2bf(float f) {
    unsigned int u = __float_as_uint(f);
    u = (u + 0x7FFFu + ((u >> 16) & 1u)) >> 16;
    return (unsigned short)u;
}
static __device__ inline float bf2f(unsigned short b) {
    return __uint_as_float(((unsigned int)b) << 16);
}

// ---------------------------------------------------------------------------
// Counting-sort each CHUNK of edges by coarse bucket (dst>>7) in LDS, then
// flush packed ((dst&127)<<17)|src words into the bucket's fixed-capacity
// region at pk[b*BCAP2 ...]. bcnt[b] (zeroed) reserves runs AND ends up as
// the exact per-bucket edge count.
__global__ __launch_bounds__(NBP) void bucket_scatter(
        const int* __restrict__ srcs, const int* __restrict__ dsts,
        int* __restrict__ bcnt, unsigned int* __restrict__ pk) {
    __shared__ int lh[NBP];                 // per-chunk bucket counts
    __shared__ int off[NBP];                // exclusive offsets -> cursors
    __shared__ int gb[NBP];                 // global_run_base - local_excl
    __shared__ unsigned int ssrc[CHUNK];
    __shared__ unsigned int sdst[CHUNK];
    int t = threadIdx.x;                    // 1024 threads
    int base = blockIdx.x * CHUNK;
    int n = NE - base; if (n > CHUNK) n = CHUNK;

    lh[t] = 0;
    __syncthreads();
    for (int i = t; i < n; i += NBP)
        atomicAdd(&lh[dsts[base + i] >> 7], 1);
    __syncthreads();
    off[t] = lh[t];
    __syncthreads();
    for (int s = 1; s < NBP; s <<= 1) {     // inclusive scan
        int v = (t >= s) ? off[t - s] : 0;
        __syncthreads();
        off[t] += v;
        __syncthreads();
    }
    int cnt  = lh[t];
    int excl = off[t] - cnt;                // own-index only: no sync needed
    off[t] = excl;                          // becomes the LDS scatter cursor
    if (cnt > 0) gb[t] = t * BCAP2 + atomicAdd(&bcnt[t], cnt) - excl;
    __syncthreads();
    for (int i = t; i < n; i += NBP) {
        int d = dsts[base + i];
        int s = srcs[base + i];
        int p = atomicAdd(&off[d >> 7], 1);
        ssrc[p] = (unsigned int)s;
        sdst[p] = (unsigned int)d;
    }
    __syncthreads();
    for (int p = t; p < n; p += NBP) {
        unsigned int d = sdst[p];
        int b = d >> 7;
        pk[gb[b] + p] = ((d & 127u) << 17) | ssrc[p];
    }
}

// ---------------------------------------------------------------------------
// One block per bucket: LDS histogram+scan over its 128 local dsts -> exact
// deg/row_start/dinv; in-LDS counting sort of srcs flushed back over the same
// pk range. Fused: Za=bf16(X*dinv) all nodes; masked nodes also get their
// static Zb and Y rows written once. Also: degree-bucket histogram (deg/8,
// unmasked only) for the gather load-balancing sort. Dummy row NN = 0.
__global__ void fine_csr(unsigned int* __restrict__ pk,
                         const int* __restrict__ bcnt,
                         const float* __restrict__ X,
                         const int* __restrict__ mask,
                         int* __restrict__ deg, int* __restrict__ row_start,
                         float* __restrict__ dinv,
                         unsigned short* __restrict__ Za,
                         unsigned short* __restrict__ Zb,
                         float* __restrict__ Y,
                         int* __restrict__ dh) {
    __shared__ int lh[128], off[128];
    __shared__ float sdi[128];
    __shared__ int ldh[DBK];
    __shared__ int sbuf[BCAP2];
    int b  = blockIdx.x;
    int t  = threadIdx.x;                   // 256 threads
    int b0 = b * BCAP2;
    int cnt = bcnt[b];
    if (t < 128) lh[t] = 0;
    if (t >= 128 && t < 128 + DBK) ldh[t - 128] = 0;
    __syncthreads();
    for (int i = t; i < cnt; i += 256)
        atomicAdd(&lh[pk[b0 + i] >> 17], 1);
    __syncthreads();
    if (t < 128) off[t] = lh[t];
    __syncthreads();
    for (int s = 1; s < 128; s <<= 1) {     // inclusive scan over 128
        int v = (t >= s && t < 128) ? off[t - s] : 0;
        __syncthreads();
        if (t < 128) off[t] += v;
        __syncthreads();
    }
    if (t < 128) {
        int c    = lh[t];
        int excl = off[t] - c;
        int dst  = (b << 7) + t;
        float di = (c > 0) ? rsqrtf((float)c) : 0.0f;
        sdi[t] = di;
        if (dst < NN) {
            deg[dst]       = c;
            row_start[dst] = b0 + excl;
            dinv[dst]      = di;
            if (mask[dst] == 0) {           // degree-bucket histogram
                int key = c >> 3; if (key > DBK - 1) key = DBK - 1;
                atomicAdd(&ldh[key], 1);
            }
        }
        off[t] = excl;                      // scatter cursor
    }
    __syncthreads();
    if (t < DBK && ldh[t]) atomicAdd(&dh[t], ldh[t]);
    for (int i = t; i < cnt; i += 256) {
        unsigned int v = pk[b0 + i];
        int p = atomicAdd(&off[v >> 17], 1);
        sbuf[p] = (int)(v & 0x1FFFFu);
    }
    __syncthreads();
    for (int i = t; i < cnt; i += 256)
        pk[b0 + i] = (unsigned int)sbuf[i]; // csr_src, sorted by local dst
    // Fused Z0/Y init
    for (int idx = t; idx < 128 * DD; idx += 256) {
        int ldst = idx >> 4;
        int ff   = idx & 15;
        int dst  = (b << 7) + ldst;
        if (dst < NN) {
            float xv = X[dst * DD + ff];
            unsigned short z = f2bf(xv * sdi[ldst]);
            Za[dst * DD + ff] = z;
            if (mask[dst] != 0) {           // static rows: write once
                Zb[dst * DD + ff] = z;
                Y[dst * DD + ff]  = xv;
            }
        }
    }
    if (b == 0 && t < DD) {                 // dummy zero row (index NN)
        Za[NN * DD + t] = 0;
        Zb[NN * DD + t] = 0;
    }
}

// ---------------------------------------------------------------------------
// Exclusive scan over the DBK degree buckets (one wave) -> bases/cursors +
// total unmasked count.
__global__ void dscan_kernel(const int* __restrict__ dh,
                             int* __restrict__ dcursor, int* __restrict__ ucount) {
    int t = threadIdx.x;                    // 64 threads
    int v = dh[t];
    int x = v;
    #pragma unroll
    for (int s = 1; s < DBK; s <<= 1) {     // inclusive wave scan
        int y = __shfl_up(x, s, DBK);
        if (t >= s) x += y;
    }
    dcursor[t] = x - v;                     // exclusive base
    if (t == DBK - 1) *ucount = x;
}

// ---------------------------------------------------------------------------
// Fill ulist grouped by degree bucket: waves in the gather kernel then see
// ~uniform-degree nodes (trip count = mean, not max-of-8; no divergence).
__global__ void dfill_kernel(const int* __restrict__ mask,
                             const int* __restrict__ deg,
                             int* __restrict__ dcursor, int* __restrict__ ulist) {
    int n = blockIdx.x * blockDim.x + threadIdx.x;
    if (n >= NN || mask[n] != 0) return;
    int key = deg[n] >> 3; if (key > DBK - 1) key = DBK - 1;
    ulist[atomicAdd(&dcursor[key], 1)] = n;
}

// ---------------------------------------------------------------------------
// Fused gather + combine over UNMASKED nodes only (degree-grouped list).
// 8 lanes per node; lane f2 owns features {2f2,2f2+1} packed in one 4B word.
// Every chunk fully unrolled; out-of-range lanes gather dummy zero row NN.
__global__ void gather_kernel(const unsigned int* __restrict__ csr_src,
                              const int* __restrict__ row_start,
                              const int* __restrict__ deg,
                              const float* __restrict__ dinv,
                              const float* __restrict__ X,
                              const int* __restrict__ ulist,
                              const int* __restrict__ ucount,
                              const unsigned short* __restrict__ Zin,
                              unsigned int* __restrict__ Zout2,
                              float2* __restrict__ Y2,
                              int last) {
    int tid = blockIdx.x * blockDim.x + threadIdx.x;  // up to NN*8
    int idx = tid >> 3;
    int f2  = tid & 7;
    if (idx >= *ucount) return;
    int node = ulist[idx];

    int start = row_start[node];
    int d     = deg[node];

    float a0 = 0.0f, a1 = 0.0f;
    for (int i = 0; i < d; i += 8) {
        int sv = (i + f2 < d)
                   ? (int)__builtin_nontemporal_load(&csr_src[start + i + f2])
                   : NN;                       // dummy zero row
        #pragma unroll
        for (int j = 0; j < 8; ++j) {
            int s = __shfl(sv, j, 8);
            unsigned int u = *(const unsigned int*)(&Zin[s * DD + 2 * f2]);
            a0 += bf2f((unsigned short)(u & 0xFFFFu));
            a1 += bf2f((unsigned short)(u >> 16));
        }
    }

    float di  = dinv[node];
    float x0  = __builtin_nontemporal_load(&X[node * DD + 2 * f2]);
    float x1  = __builtin_nontemporal_load(&X[node * DD + 2 * f2 + 1]);
    float v0  = GAMMA * a0 * di + ALP * x0;
    float v1  = GAMMA * a1 * di + ALP * x1;
    v0 = fminf(fmaxf(v0, -1.0f), 1.0f);
    v1 = fminf(fmaxf(v1, -1.0f), 1.0f);
    if (last) {
        Y2[node * 8 + f2] = make_float2(v0, v1);
    } else {
        unsigned int p = (unsigned int)f2bf(v0 * di)
                       | ((unsigned int)f2bf(v1 * di) << 16);
        Zout2[node * 8 + f2] = p;
    }
}

// ---------------------------------------------------------------------------
extern "C" void kernel_launch(void* const* d_in, const int* in_sizes, int n_in,
                              void* d_out, int out_size, void* d_ws, size_t ws_size,
                              hipStream_t stream) {
    const int*   edge_index = (const int*)d_in[0];   // (2, E) int32
    const float* X          = (const float*)d_in[1]; // (N, 16) f32
    const int*   mask       = (const int*)d_in[2];   // (N,) bool as int32

    const int* srcs = edge_index;        // row 0
    const int* dsts = edge_index + NE;   // row 1

    float* Y = (float*)d_out;            // (N, 16) f32 output

    // workspace layout (~24 MB). memset covers bcnt + ucount + dh.
    int*   bcnt      = (int*)d_ws;                   // NBP
    int*   ucount    = bcnt + NBP;                   // 1
    int*   dh        = ucount + 1;                   // DBK
    int*   dcursor   = dh + DBK;                     // DBK
    int*   ulist     = dcursor + DBK;                // NN
    int*   deg       = ulist + NN;                   // NN
    int*   row_start = deg + NN;                     // NN
    float* dinv      = (float*)(row_start + NN);     // NN
    unsigned int* pk = (unsigned int*)(dinv + NN);   // NB*BCAP2 (csr aliases)
    unsigned short* Za = (unsigned short*)(pk + NB * BCAP2); // (NN+1)*DD bf16
    unsigned short* Zb = Za + (NN + 1) * DD;                 // (NN+1)*DD bf16

    (void)hipMemsetAsync(bcnt, 0, (NBP + 1 + DBK) * sizeof(int), stream);

    bucket_scatter<<<NCHUNK, NBP, 0, stream>>>(srcs, dsts, bcnt, pk);
    fine_csr<<<NB, 256, 0, stream>>>(pk, bcnt, X, mask, deg, row_start, dinv,
                                     Za, Zb, Y, dh);
    dscan_kernel<<<1, DBK, 0, stream>>>(dh, dcursor, ucount);
    dfill_kernel<<<(NN + 255) / 256, 256, 0, stream>>>(mask, deg, dcursor, ulist);

    // Z ping-pong: Za -> Zb -> Za -> Zb -> Za -> Y(last)
    const unsigned short* zin  = Za;
    unsigned short*       zout = Zb;
    for (int t = 0; t < 5; ++t) {
        int last = (t == 4);
        gather_kernel<<<(NN * 8) / 256, 256, 0, stream>>>(
            pk, row_start, deg, dinv, X, ulist, ucount,
            zin, (unsigned int*)zout, (float2*)Y, last);
        const unsigned short* tmp = zout;
        zout = (unsigned short*)zin;
        zin  = tmp;
    }
}

// Round 12
// 259.810 us; speedup vs baseline: 2.2889x; 2.2889x over previous
//
#include <hip/hip_runtime.h>

// Problem constants (fixed by the reference)
#define NN 100000
#define NE 3200000
#define DD 16
#define NB 782              // ceil(NN / 128) coarse buckets (128 dsts each)
#define NBP 1024            // padded bucket count
#define CHUNK 8192          // edges per bucket_scatter block
#define NCHUNK ((NE + CHUNK - 1) / CHUNK)   // 391
#define BCAP2 4864          // fixed capacity per bucket (mean 4092 + 12 sigma)
#define DBK 64              // degree buckets for gather load-balancing

constexpr float LAM   = 1.0f;
constexpr float ALP   = 1.0f / (LAM + 1.0f);   // 0.5
constexpr float GAMMA = ALP * LAM;             // 0.5
// (1 - ALP - ALP*LAM) == 0 at these constants -> no Y carry term

// bf16 helpers: RTNE pack, cheap unpack
static __device__ inline unsigned short f2bf(float f) {
    unsigned int u = __float_as_uint(f);
    u = (u + 0x7FFFu + ((u >> 16) & 1u)) >> 16;
    return (unsigned short)u;
}
static __device__ inline float bf2f(unsigned short b) {
    return __uint_as_float(((unsigned int)b) << 16);
}

// ---------------------------------------------------------------------------
// Counting-sort each CHUNK of edges by coarse bucket (dst>>7) in LDS, then
// flush packed ((dst&127)<<17)|src words into the bucket's fixed-capacity
// region at pk[b*BCAP2 ...]. bcnt[b] (zeroed) reserves runs AND ends up as
// the exact per-bucket edge count.
__global__ __launch_bounds__(NBP) void bucket_scatter(
        const int* __restrict__ srcs, const int* __restrict__ dsts,
        int* __restrict__ bcnt, unsigned int* __restrict__ pk) {
    __shared__ int lh[NBP];                 // per-chunk bucket counts
    __shared__ int off[NBP];                // exclusive offsets -> cursors
    __shared__ int gb[NBP];                 // global_run_base - local_excl
    __shared__ unsigned int ssrc[CHUNK];
    __shared__ unsigned int sdst[CHUNK];
    int t = threadIdx.x;                    // 1024 threads
    int base = blockIdx.x * CHUNK;
    int n = NE - base; if (n > CHUNK) n = CHUNK;

    lh[t] = 0;
    __syncthreads();
    for (int i = t; i < n; i += NBP)
        atomicAdd(&lh[dsts[base + i] >> 7], 1);
    __syncthreads();
    off[t] = lh[t];
    __syncthreads();
    for (int s = 1; s < NBP; s <<= 1) {     // inclusive scan
        int v = (t >= s) ? off[t - s] : 0;
        __syncthreads();
        off[t] += v;
        __syncthreads();
    }
    int cnt  = lh[t];
    int excl = off[t] - cnt;                // own-index only: no sync needed
    off[t] = excl;                          // becomes the LDS scatter cursor
    if (cnt > 0) gb[t] = t * BCAP2 + atomicAdd(&bcnt[t], cnt) - excl;
    __syncthreads();
    for (int i = t; i < n; i += NBP) {
        int d = dsts[base + i];
        int s = srcs[base + i];
        int p = atomicAdd(&off[d >> 7], 1);
        ssrc[p] = (unsigned int)s;
        sdst[p] = (unsigned int)d;
    }
    __syncthreads();
    for (int p = t; p < n; p += NBP) {
        unsigned int d = sdst[p];
        int b = d >> 7;
        pk[gb[b] + p] = ((d & 127u) << 17) | ssrc[p];
    }
}

// ---------------------------------------------------------------------------
// One block per bucket: LDS histogram+scan over its 128 local dsts -> exact
// deg/row_start/dinv; in-LDS counting sort of srcs flushed back over the same
// pk range. Fused: Za=bf16(X*dinv) all nodes; masked nodes also get their
// static Zb and Y rows written once. Also: degree-bucket histogram (deg/8,
// unmasked only) for the gather load-balancing sort. Dummy row NN = 0.
__global__ void fine_csr(unsigned int* __restrict__ pk,
                         const int* __restrict__ bcnt,
                         const float* __restrict__ X,
                         const int* __restrict__ mask,
                         int* __restrict__ deg, int* __restrict__ row_start,
                         float* __restrict__ dinv,
                         unsigned short* __restrict__ Za,
                         unsigned short* __restrict__ Zb,
                         float* __restrict__ Y,
                         int* __restrict__ dh) {
    __shared__ int lh[128], off[128];
    __shared__ float sdi[128];
    __shared__ int ldh[DBK];
    __shared__ int sbuf[BCAP2];
    int b  = blockIdx.x;
    int t  = threadIdx.x;                   // 256 threads
    int b0 = b * BCAP2;
    int cnt = bcnt[b];
    if (t < 128) lh[t] = 0;
    if (t >= 128 && t < 128 + DBK) ldh[t - 128] = 0;
    __syncthreads();
    for (int i = t; i < cnt; i += 256)
        atomicAdd(&lh[pk[b0 + i] >> 17], 1);
    __syncthreads();
    if (t < 128) off[t] = lh[t];
    __syncthreads();
    for (int s = 1; s < 128; s <<= 1) {     // inclusive scan over 128
        int v = (t >= s && t < 128) ? off[t - s] : 0;
        __syncthreads();
        if (t < 128) off[t] += v;
        __syncthreads();
    }
    if (t < 128) {
        int c    = lh[t];
        int excl = off[t] - c;
        int dst  = (b << 7) + t;
        float di = (c > 0) ? rsqrtf((float)c) : 0.0f;
        sdi[t] = di;
        if (dst < NN) {
            deg[dst]       = c;
            row_start[dst] = b0 + excl;
            dinv[dst]      = di;
            if (mask[dst] == 0) {           // degree-bucket histogram
                int key = c >> 3; if (key > DBK - 1) key = DBK - 1;
                atomicAdd(&ldh[key], 1);
            }
        }
        off[t] = excl;                      // scatter cursor
    }
    __syncthreads();
    if (t < DBK && ldh[t]) atomicAdd(&dh[t], ldh[t]);
    for (int i = t; i < cnt; i += 256) {
        unsigned int v = pk[b0 + i];
        int p = atomicAdd(&off[v >> 17], 1);
        sbuf[p] = (int)(v & 0x1FFFFu);
    }
    __syncthreads();
    for (int i = t; i < cnt; i += 256)
        pk[b0 + i] = (unsigned int)sbuf[i]; // csr_src, sorted by local dst
    // Fused Z0/Y init
    for (int idx = t; idx < 128 * DD; idx += 256) {
        int ldst = idx >> 4;
        int ff   = idx & 15;
        int dst  = (b << 7) + ldst;
        if (dst < NN) {
            float xv = X[dst * DD + ff];
            unsigned short z = f2bf(xv * sdi[ldst]);
            Za[dst * DD + ff] = z;
            if (mask[dst] != 0) {           // static rows: write once
                Zb[dst * DD + ff] = z;
                Y[dst * DD + ff]  = xv;
            }
        }
    }
    if (b == 0 && t < DD) {                 // dummy zero row (index NN)
        Za[NN * DD + t] = 0;
        Zb[NN * DD + t] = 0;
    }
}

// ---------------------------------------------------------------------------
// Exclusive scan over the DBK degree buckets (one wave) -> bases/cursors +
// total unmasked count.
__global__ void dscan_kernel(const int* __restrict__ dh,
                             int* __restrict__ dcursor, int* __restrict__ ucount) {
    int t = threadIdx.x;                    // 64 threads
    int v = dh[t];
    int x = v;
    #pragma unroll
    for (int s = 1; s < DBK; s <<= 1) {     // inclusive wave scan
        int y = __shfl_up(x, s, DBK);
        if (t >= s) x += y;
    }
    dcursor[t] = x - v;                     // exclusive base
    if (t == DBK - 1) *ucount = x;
}

// ---------------------------------------------------------------------------
// Fill ulist grouped by degree bucket — LDS-aggregated (one global atomic per
// block×bucket, NOT per node: 50K same-address atomics was a 338 µs disaster).
__global__ void dfill_kernel(const int* __restrict__ mask,
                             const int* __restrict__ deg,
                             int* __restrict__ dcursor, int* __restrict__ ulist) {
    __shared__ int lh[DBK];     // local histogram -> local cursor
    __shared__ int gb[DBK];     // global_run_base - local_excl
    int t = threadIdx.x;        // 256 threads, 256 nodes per block
    int n = blockIdx.x * 256 + t;
    bool active = (n < NN) && (mask[n] == 0);
    int key = 0;
    if (active) {
        key = deg[n] >> 3; if (key > DBK - 1) key = DBK - 1;
    }
    if (t < DBK) lh[t] = 0;
    __syncthreads();
    int lpos = active ? atomicAdd(&lh[key], 1) : 0;   // local rank in bucket
    __syncthreads();
    if (t < DBK) {
        int c = lh[t];
        // exclusive scan over 64 buckets within one wave (t<64 => one wave)
        int x = c;
        #pragma unroll
        for (int s = 1; s < DBK; s <<= 1) {
            int y = __shfl_up(x, s, DBK);
            if ((t & 63) >= s) x += y;
        }
        (void)x;  // (scan not needed: runs are per-bucket, not packed)
        gb[t] = (c > 0) ? atomicAdd(&dcursor[t], c) : 0;
    }
    __syncthreads();
    if (active) ulist[gb[key] + lpos] = n;
}

// ---------------------------------------------------------------------------
// Fused gather + combine over UNMASKED nodes only (degree-grouped list).
// 8 lanes per node; lane f2 owns features {2f2,2f2+1} packed in one 4B word.
// Every chunk fully unrolled; out-of-range lanes gather dummy zero row NN.
__global__ void gather_kernel(const unsigned int* __restrict__ csr_src,
                              const int* __restrict__ row_start,
                              const int* __restrict__ deg,
                              const float* __restrict__ dinv,
                              const float* __restrict__ X,
                              const int* __restrict__ ulist,
                              const int* __restrict__ ucount,
                              const unsigned short* __restrict__ Zin,
                              unsigned int* __restrict__ Zout2,
                              float2* __restrict__ Y2,
                              int last) {
    int tid = blockIdx.x * blockDim.x + threadIdx.x;  // up to NN*8
    int idx = tid >> 3;
    int f2  = tid & 7;
    if (idx >= *ucount) return;
    int node = ulist[idx];

    int start = row_start[node];
    int d     = deg[node];

    float a0 = 0.0f, a1 = 0.0f;
    for (int i = 0; i < d; i += 8) {
        int sv = (i + f2 < d)
                   ? (int)__builtin_nontemporal_load(&csr_src[start + i + f2])
                   : NN;                       // dummy zero row
        #pragma unroll
        for (int j = 0; j < 8; ++j) {
            int s = __shfl(sv, j, 8);
            unsigned int u = *(const unsigned int*)(&Zin[s * DD + 2 * f2]);
            a0 += bf2f((unsigned short)(u & 0xFFFFu));
            a1 += bf2f((unsigned short)(u >> 16));
        }
    }

    float di  = dinv[node];
    float x0  = __builtin_nontemporal_load(&X[node * DD + 2 * f2]);
    float x1  = __builtin_nontemporal_load(&X[node * DD + 2 * f2 + 1]);
    float v0  = GAMMA * a0 * di + ALP * x0;
    float v1  = GAMMA * a1 * di + ALP * x1;
    v0 = fminf(fmaxf(v0, -1.0f), 1.0f);
    v1 = fminf(fmaxf(v1, -1.0f), 1.0f);
    if (last) {
        Y2[node * 8 + f2] = make_float2(v0, v1);
    } else {
        unsigned int p = (unsigned int)f2bf(v0 * di)
                       | ((unsigned int)f2bf(v1 * di) << 16);
        Zout2[node * 8 + f2] = p;
    }
}

// ---------------------------------------------------------------------------
extern "C" void kernel_launch(void* const* d_in, const int* in_sizes, int n_in,
                              void* d_out, int out_size, void* d_ws, size_t ws_size,
                              hipStream_t stream) {
    const int*   edge_index = (const int*)d_in[0];   // (2, E) int32
    const float* X          = (const float*)d_in[1]; // (N, 16) f32
    const int*   mask       = (const int*)d_in[2];   // (N,) bool as int32

    const int* srcs = edge_index;        // row 0
    const int* dsts = edge_index + NE;   // row 1

    float* Y = (float*)d_out;            // (N, 16) f32 output

    // workspace layout (~24 MB). memset covers bcnt + ucount + dh.
    int*   bcnt      = (int*)d_ws;                   // NBP
    int*   ucount    = bcnt + NBP;                   // 1
    int*   dh        = ucount + 1;                   // DBK
    int*   dcursor   = dh + DBK;                     // DBK
    int*   ulist     = dcursor + DBK;                // NN
    int*   deg       = ulist + NN;                   // NN
    int*   row_start = deg + NN;                     // NN
    float* dinv      = (float*)(row_start + NN);     // NN
    unsigned int* pk = (unsigned int*)(dinv + NN);   // NB*BCAP2 (csr aliases)
    unsigned short* Za = (unsigned short*)(pk + NB * BCAP2); // (NN+1)*DD bf16
    unsigned short* Zb = Za + (NN + 1) * DD;                 // (NN+1)*DD bf16

    (void)hipMemsetAsync(bcnt, 0, (NBP + 1 + DBK) * sizeof(int), stream);

    bucket_scatter<<<NCHUNK, NBP, 0, stream>>>(srcs, dsts, bcnt, pk);
    fine_csr<<<NB, 256, 0, stream>>>(pk, bcnt, X, mask, deg, row_start, dinv,
                                     Za, Zb, Y, dh);
    dscan_kernel<<<1, DBK, 0, stream>>>(dh, dcursor, ucount);
    dfill_kernel<<<(NN + 255) / 256, 256, 0, stream>>>(mask, deg, dcursor, ulist);

    // Z ping-pong: Za -> Zb -> Za -> Zb -> Za -> Y(last)
    const unsigned short* zin  = Za;
    unsigned short*       zout = Zb;
    for (int t = 0; t < 5; ++t) {
        int last = (t == 4);
        gather_kernel<<<(NN * 8) / 256, 256, 0, stream>>>(
            pk, row_start, deg, dinv, X, ulist, ucount,
            zin, (unsigned int*)zout, (float2*)Y, last);
        const unsigned short* tmp = zout;
        zout = (unsigned short*)zin;
        zin  = tmp;
    }
}

// Round 13
// 225.870 us; speedup vs baseline: 2.6329x; 1.1503x over previous
//
#include <hip/hip_runtime.h>

// Problem constants (fixed by the reference)
#define NN 100000
#define NE 3200000
#define DD 16
#define NB 782              // ceil(NN / 128) coarse buckets (128 dsts each)
#define NBP 1024            // padded bucket count
#define CHUNK 8192          // edges per bucket_scatter block
#define NCHUNK ((NE + CHUNK - 1) / CHUNK)   // 391
#define BCAP2 4864          // fixed capacity per bucket (mean 4092 + 12 sigma)
#define DBK 64              // degree buckets for gather load-balancing
#define BMW 3128            // u32 words of the node mask bitmap (2*1564)

constexpr float LAM   = 1.0f;
constexpr float ALP   = 1.0f / (LAM + 1.0f);   // 0.5
constexpr float GAMMA = ALP * LAM;             // 0.5
// (1 - ALP - ALP*LAM) == 0 at these constants -> no Y carry term

static __device__ inline unsigned short f2bf(float f) {   // RTNE pack
    unsigned int u = __float_as_uint(f);
    u = (u + 0x7FFFu + ((u >> 16) & 1u)) >> 16;
    return (unsigned short)u;
}
static __device__ inline float uf(unsigned int u) { return __uint_as_float(u); }

// ---------------------------------------------------------------------------
// Node mask bitmap: bit n = (mask[n] != 0). One u64 per wave via ballot.
__global__ void bitmap_kernel(const int* __restrict__ mask,
                              unsigned long long* __restrict__ bm64) {
    int n = blockIdx.x * blockDim.x + threadIdx.x;
    bool b = (n < NN) && (mask[n] != 0);
    unsigned long long bal = __ballot(b);
    if ((threadIdx.x & 63) == 0) bm64[n >> 6] = bal;
}

// ---------------------------------------------------------------------------
// Counting-sort each CHUNK of edges by coarse bucket (dst>>7) in LDS, then
// flush packed ((dst&127)<<17)|src words into pk[b*BCAP2 ...]. bcnt[b]
// (zeroed) reserves runs AND ends up as the exact per-bucket edge count.
__global__ __launch_bounds__(NBP) void bucket_scatter(
        const int* __restrict__ srcs, const int* __restrict__ dsts,
        int* __restrict__ bcnt, unsigned int* __restrict__ pk) {
    __shared__ int lh[NBP];
    __shared__ int off[NBP];
    __shared__ int gb[NBP];
    __shared__ unsigned int ssrc[CHUNK];
    __shared__ unsigned int sdst[CHUNK];
    int t = threadIdx.x;                    // 1024 threads
    int base = blockIdx.x * CHUNK;
    int n = NE - base; if (n > CHUNK) n = CHUNK;

    lh[t] = 0;
    __syncthreads();
    for (int i = t; i < n; i += NBP)
        atomicAdd(&lh[dsts[base + i] >> 7], 1);
    __syncthreads();
    off[t] = lh[t];
    __syncthreads();
    for (int s = 1; s < NBP; s <<= 1) {     // inclusive scan
        int v = (t >= s) ? off[t - s] : 0;
        __syncthreads();
        off[t] += v;
        __syncthreads();
    }
    int cnt  = lh[t];
    int excl = off[t] - cnt;
    off[t] = excl;                          // LDS scatter cursor
    if (cnt > 0) gb[t] = t * BCAP2 + atomicAdd(&bcnt[t], cnt) - excl;
    __syncthreads();
    for (int i = t; i < n; i += NBP) {
        int d = dsts[base + i];
        int s = srcs[base + i];
        int p = atomicAdd(&off[d >> 7], 1);
        ssrc[p] = (unsigned int)s;
        sdst[p] = (unsigned int)d;
    }
    __syncthreads();
    for (int p = t; p < n; p += NBP) {
        unsigned int d = sdst[p];
        int b = d >> 7;
        pk[gb[b] + p] = ((d & 127u) << 17) | ssrc[p];
    }
}

// ---------------------------------------------------------------------------
// One block per bucket. 256 sub-buckets: key = local_dst*2 + (src masked?0:1)
// -> per dst: [static(masked-src) | dynamic(unmasked-src)] segments.
// Outputs row_start (static start), mid (dynamic start), dend (end), dinv.
// Fused: Za=bf16(X*dinv) all nodes; masked dsts get static Zb/Y rows once;
// degree-bucket histogram on DYNAMIC degree (unmasked dsts). Dummy row NN=0.
__global__ void fine_csr(unsigned int* __restrict__ pk,
                         const int* __restrict__ bcnt,
                         const float* __restrict__ X,
                         const unsigned int* __restrict__ bitmap,
                         int* __restrict__ row_start, int* __restrict__ midp,
                         int* __restrict__ dendp,
                         float* __restrict__ dinv,
                         unsigned short* __restrict__ Za,
                         unsigned short* __restrict__ Zb,
                         float* __restrict__ Y,
                         int* __restrict__ dh) {
    __shared__ int lh[256], off[256];
    __shared__ float sdi[128];
    __shared__ int ldh[DBK];
    __shared__ unsigned int bmp[BMW];
    __shared__ int sbuf[BCAP2];
    int b  = blockIdx.x;
    int t  = threadIdx.x;                   // 256 threads
    int b0 = b * BCAP2;
    int cnt = bcnt[b];
    lh[t] = 0;
    if (t < DBK) ldh[t] = 0;
    for (int i = t; i < BMW; i += 256) bmp[i] = bitmap[i];
    __syncthreads();
    for (int i = t; i < cnt; i += 256) {
        unsigned int v = pk[b0 + i];
        unsigned int s = v & 0x1FFFFu;
        int mb = (bmp[s >> 5] >> (s & 31)) & 1;
        atomicAdd(&lh[((v >> 17) << 1) | (mb ? 0 : 1)], 1);
    }
    __syncthreads();
    off[t] = lh[t];
    __syncthreads();
    for (int s = 1; s < 256; s <<= 1) {     // inclusive scan over 256
        int v = (t >= s) ? off[t - s] : 0;
        __syncthreads();
        off[t] += v;
        __syncthreads();
    }
    int myexcl = off[t] - lh[t];
    if (t < 128) {                          // per-dst outputs (reads stable off)
        int cs = lh[2 * t], cd = lh[2 * t + 1];
        int es = off[2 * t] - cs;           // static excl
        int ed = off[2 * t + 1] - cd;       // dynamic excl (= es + cs)
        int c  = cs + cd;
        int dst = (b << 7) + t;
        float di = (c > 0) ? rsqrtf((float)c) : 0.0f;
        sdi[t] = di;
        if (dst < NN) {
            row_start[dst] = b0 + es;
            midp[dst]      = b0 + ed;
            dendp[dst]     = b0 + ed + cd;
            dinv[dst]      = di;
            if (((bmp[dst >> 5] >> (dst & 31)) & 1) == 0) {
                int key = cd >> 3; if (key > DBK - 1) key = DBK - 1;
                atomicAdd(&ldh[key], 1);
            }
        }
    }
    __syncthreads();
    off[t] = myexcl;                        // becomes the scatter cursor
    if (t < DBK && ldh[t]) atomicAdd(&dh[t], ldh[t]);
    __syncthreads();
    for (int i = t; i < cnt; i += 256) {
        unsigned int v = pk[b0 + i];
        unsigned int s = v & 0x1FFFFu;
        int mb = (bmp[s >> 5] >> (s & 31)) & 1;
        int p = atomicAdd(&off[((v >> 17) << 1) | (mb ? 0 : 1)], 1);
        sbuf[p] = (int)s;
    }
    __syncthreads();
    for (int i = t; i < cnt; i += 256)
        pk[b0 + i] = (unsigned int)sbuf[i]; // csr: per dst [static|dynamic]
    // Fused Z0/Y init
    for (int idx = t; idx < 128 * DD; idx += 256) {
        int ldst = idx >> 4;
        int ff   = idx & 15;
        int dst  = (b << 7) + ldst;
        if (dst < NN) {
            float xv = X[dst * DD + ff];
            unsigned short z = f2bf(xv * sdi[ldst]);
            Za[dst * DD + ff] = z;
            if ((bmp[dst >> 5] >> (dst & 31)) & 1) {   // masked: static rows
                Zb[dst * DD + ff] = z;
                Y[dst * DD + ff]  = xv;
            }
        }
    }
    if (b == 0 && t < DD) {                 // dummy zero row (index NN)
        Za[NN * DD + t] = 0;
        Zb[NN * DD + t] = 0;
    }
}

// ---------------------------------------------------------------------------
// Exclusive scan over the DBK degree buckets (one wave).
__global__ void dscan_kernel(const int* __restrict__ dh,
                             int* __restrict__ dcursor, int* __restrict__ ucount) {
    int t = threadIdx.x;                    // 64 threads
    int v = dh[t];
    int x = v;
    #pragma unroll
    for (int s = 1; s < DBK; s <<= 1) {
        int y = __shfl_up(x, s, DBK);
        if (t >= s) x += y;
    }
    dcursor[t] = x - v;
    if (t == DBK - 1) *ucount = x;
}

// ---------------------------------------------------------------------------
// Fill ulist grouped by dynamic-degree bucket; LDS-aggregated reservations.
__global__ void dfill_kernel(const int* __restrict__ mask,
                             const int* __restrict__ midp,
                             const int* __restrict__ dendp,
                             int* __restrict__ dcursor, int* __restrict__ ulist) {
    __shared__ int lh[DBK];
    __shared__ int gb[DBK];
    int t = threadIdx.x;        // 256 threads, 256 nodes per block
    int n = blockIdx.x * 256 + t;
    bool active = (n < NN) && (mask[n] == 0);
    int key = 0;
    if (active) {
        key = (dendp[n] - midp[n]) >> 3; if (key > DBK - 1) key = DBK - 1;
    }
    if (t < DBK) lh[t] = 0;
    __syncthreads();
    int lpos = active ? atomicAdd(&lh[key], 1) : 0;
    __syncthreads();
    if (t < DBK) gb[t] = (lh[t] > 0) ? atomicAdd(&dcursor[t], lh[t]) : 0;
    __syncthreads();
    if (active) ulist[gb[key] + lpos] = n;
}

// ---------------------------------------------------------------------------
// 8-lane-group fold: after log2(8)=3 steps each lane holds the group-total of
// features {fp, fp+1}, fp = 8*(ln&1) + 4*((ln>>1)&1) + 2*((ln>>2)&1).
static __device__ inline void fold8(float* acc, int ln) {
    {
        int sel = ln & 1;
        #pragma unroll
        for (int k = 0; k < 8; ++k) {
            float mine   = sel ? acc[k + 8] : acc[k];
            float theirs = sel ? acc[k]     : acc[k + 8];
            acc[k] = mine + __shfl_xor(theirs, 1, 8);
        }
    }
    {
        int sel = (ln >> 1) & 1;
        #pragma unroll
        for (int k = 0; k < 4; ++k) {
            float mine   = sel ? acc[k + 4] : acc[k];
            float theirs = sel ? acc[k]     : acc[k + 4];
            acc[k] = mine + __shfl_xor(theirs, 2, 8);
        }
    }
    {
        int sel = (ln >> 2) & 1;
        #pragma unroll
        for (int k = 0; k < 2; ++k) {
            float mine   = sel ? acc[k + 2] : acc[k];
            float theirs = sel ? acc[k]     : acc[k + 2];
            acc[k] = mine + __shfl_xor(theirs, 4, 8);
        }
    }
}

// Accumulate one csr range [lo,hi) into acc[16]; neighbor-per-lane, no
// bpermute: each lane loads a whole 32B bf16 row with 2x dwordx4.
static __device__ inline void accum_range(const unsigned int* __restrict__ csr,
                                          const unsigned int* __restrict__ Zrow,
                                          int lo, int hi, int ln, float* acc) {
    for (int i = lo; i < hi; i += 8) {
        int p = i + ln;
        int s = (p < hi) ? (int)__builtin_nontemporal_load((const int*)&csr[p]) : NN;
        const uint4* rp = (const uint4*)(Zrow + (size_t)s * 8);
        uint4 r0 = rp[0];
        uint4 r1 = rp[1];
        acc[0]  += uf(r0.x << 16); acc[1]  += uf(r0.x & 0xFFFF0000u);
        acc[2]  += uf(r0.y << 16); acc[3]  += uf(r0.y & 0xFFFF0000u);
        acc[4]  += uf(r0.z << 16); acc[5]  += uf(r0.z & 0xFFFF0000u);
        acc[6]  += uf(r0.w << 16); acc[7]  += uf(r0.w & 0xFFFF0000u);
        acc[8]  += uf(r1.x << 16); acc[9]  += uf(r1.x & 0xFFFF0000u);
        acc[10] += uf(r1.y << 16); acc[11] += uf(r1.y & 0xFFFF0000u);
        acc[12] += uf(r1.z << 16); acc[13] += uf(r1.z & 0xFFFF0000u);
        acc[14] += uf(r1.w << 16); acc[15] += uf(r1.w & 0xFFFF0000u);
    }
}

// ---------------------------------------------------------------------------
// One-time static pass: Sst2[node] = GAMMA*dinv*Sum_{masked src} Z + ALP*X.
__global__ void static_gather(const unsigned int* __restrict__ csr,
                              const int* __restrict__ row_start,
                              const int* __restrict__ midp,
                              const float* __restrict__ dinv,
                              const float* __restrict__ X,
                              const int* __restrict__ ulist,
                              const int* __restrict__ ucount,
                              const unsigned int* __restrict__ Zrow,
                              float2* __restrict__ Sst2) {
    int tid = blockIdx.x * blockDim.x + threadIdx.x;
    int idx = tid >> 3;
    int ln  = tid & 7;
    if (idx >= *ucount) return;
    int node = ulist[idx];
    int lo = row_start[node], hi = midp[node];

    float acc[16];
    #pragma unroll
    for (int k = 0; k < 16; ++k) acc[k] = 0.0f;
    accum_range(csr, Zrow, lo, hi, ln, acc);
    fold8(acc, ln);
    int fp = 8 * (ln & 1) + 4 * ((ln >> 1) & 1) + 2 * ((ln >> 2) & 1);
    float di = dinv[node];
    float x0 = __builtin_nontemporal_load(&X[node * DD + fp]);
    float x1 = __builtin_nontemporal_load(&X[node * DD + fp + 1]);
    Sst2[node * 8 + (fp >> 1)] =
        make_float2(GAMMA * acc[0] * di + ALP * x0,
                    GAMMA * acc[1] * di + ALP * x1);
}

// ---------------------------------------------------------------------------
// Per-iteration pass over dynamic (unmasked->unmasked) edges only:
// v = clip(Sst + GAMMA*dinv*Sum_dyn Z); last ? Y : Zout = bf16(v*dinv).
__global__ void gather_kernel(const unsigned int* __restrict__ csr,
                              const int* __restrict__ midp,
                              const int* __restrict__ dendp,
                              const float* __restrict__ dinv,
                              const float2* __restrict__ Sst2,
                              const int* __restrict__ ulist,
                              const int* __restrict__ ucount,
                              const unsigned int* __restrict__ Zrow,
                              unsigned int* __restrict__ Zout2,
                              float2* __restrict__ Y2,
                              int last) {
    int tid = blockIdx.x * blockDim.x + threadIdx.x;
    int idx = tid >> 3;
    int ln  = tid & 7;
    if (idx >= *ucount) return;
    int node = ulist[idx];
    int lo = midp[node], hi = dendp[node];

    float acc[16];
    #pragma unroll
    for (int k = 0; k < 16; ++k) acc[k] = 0.0f;
    accum_range(csr, Zrow, lo, hi, ln, acc);
    fold8(acc, ln);
    int fp = 8 * (ln & 1) + 4 * ((ln >> 1) & 1) + 2 * ((ln >> 2) & 1);
    float di = dinv[node];
    float2 sst = Sst2[node * 8 + (fp >> 1)];
    float v0 = sst.x + GAMMA * acc[0] * di;
    float v1 = sst.y + GAMMA * acc[1] * di;
    v0 = fminf(fmaxf(v0, -1.0f), 1.0f);
    v1 = fminf(fmaxf(v1, -1.0f), 1.0f);
    if (last) {
        Y2[node * 8 + (fp >> 1)] = make_float2(v0, v1);
    } else {
        unsigned int p = (unsigned int)f2bf(v0 * di)
                       | ((unsigned int)f2bf(v1 * di) << 16);
        Zout2[node * 8 + (fp >> 1)] = p;
    }
}

// ---------------------------------------------------------------------------
extern "C" void kernel_launch(void* const* d_in, const int* in_sizes, int n_in,
                              void* d_out, int out_size, void* d_ws, size_t ws_size,
                              hipStream_t stream) {
    const int*   edge_index = (const int*)d_in[0];   // (2, E) int32
    const float* X          = (const float*)d_in[1]; // (N, 16) f32
    const int*   mask       = (const int*)d_in[2];   // (N,) bool as int32

    const int* srcs = edge_index;        // row 0
    const int* dsts = edge_index + NE;   // row 1

    float* Y = (float*)d_out;            // (N, 16) f32 output

    // workspace layout (~30 MB; 16B-aligned Z rows first)
    unsigned short* Za = (unsigned short*)d_ws;              // (NN+1)*DD bf16
    unsigned short* Zb = Za + (NN + 1) * DD;                 // (NN+1)*DD bf16
    float* Sst         = (float*)(Zb + (NN + 1) * DD);       // NN*DD f32
    unsigned int* pk   = (unsigned int*)(Sst + NN * DD);     // NB*BCAP2
    int*   bcnt      = (int*)(pk + NB * BCAP2);              // NBP
    int*   ucount    = bcnt + NBP;                           // 1
    int*   dh        = ucount + 1;                           // DBK
    int*   dcursor   = dh + DBK;                             // DBK
    int*   pad       = dcursor + DBK;                        // 1 (align)
    unsigned int* bitmap = (unsigned int*)(pad + 1);         // BMW (8B-aligned)
    int*   ulist     = (int*)(bitmap + BMW);                 // NN
    int*   midp      = ulist + NN;                           // NN
    int*   dendp     = midp + NN;                            // NN
    int*   row_start = dendp + NN;                           // NN
    float* dinv      = (float*)(row_start + NN);             // NN

    (void)hipMemsetAsync(bcnt, 0, (NBP + 1 + DBK) * sizeof(int), stream);

    bitmap_kernel<<<(NN + 255) / 256, 256, 0, stream>>>(
        mask, (unsigned long long*)bitmap);
    bucket_scatter<<<NCHUNK, NBP, 0, stream>>>(srcs, dsts, bcnt, pk);
    fine_csr<<<NB, 256, 0, stream>>>(pk, bcnt, X, bitmap, row_start, midp, dendp,
                                     dinv, Za, Zb, Y, dh);
    dscan_kernel<<<1, DBK, 0, stream>>>(dh, dcursor, ucount);
    dfill_kernel<<<(NN + 255) / 256, 256, 0, stream>>>(mask, midp, dendp,
                                                       dcursor, ulist);
    static_gather<<<(NN * 8) / 256, 256, 0, stream>>>(
        pk, row_start, midp, dinv, X, ulist, ucount,
        (const unsigned int*)Za, (float2*)Sst);

    // Z ping-pong: Za -> Zb -> Za -> Zb -> Za -> Y(last)
    const unsigned short* zin  = Za;
    unsigned short*       zout = Zb;
    for (int t = 0; t < 5; ++t) {
        int last = (t == 4);
        gather_kernel<<<(NN * 8) / 256, 256, 0, stream>>>(
            pk, midp, dendp, dinv, (const float2*)Sst, ulist, ucount,
            (const unsigned int*)zin, (unsigned int*)zout, (float2*)Y, last);
        const unsigned short* tmp = zout;
        zout = (unsigned short*)zin;
        zin  = tmp;
    }
}

// Round 14
// 218.228 us; speedup vs baseline: 2.7251x; 1.0350x over previous
//
#include <hip/hip_runtime.h>

// Problem constants (fixed by the reference)
#define NN 100000
#define NE 3200000
#define DD 16
#define NB 782              // ceil(NN / 128) coarse buckets (128 dsts each)
#define NBP 1024            // padded bucket count
#define CHUNK 8192          // edges per bucket_scatter block
#define NCHUNK ((NE + CHUNK - 1) / CHUNK)   // 391
#define BCAP2 4864          // fixed capacity per bucket (mean 4092 + 12 sigma)
#define BMW 3128            // u32 words of the node mask bitmap

constexpr float LAM   = 1.0f;
constexpr float ALP   = 1.0f / (LAM + 1.0f);   // 0.5
constexpr float GAMMA = ALP * LAM;             // 0.5
// (1 - ALP - ALP*LAM) == 0 at these constants -> no Y carry term

static __device__ inline unsigned short f2bf(float f) {   // RTNE pack
    unsigned int u = __float_as_uint(f);
    u = (u + 0x7FFFu + ((u >> 16) & 1u)) >> 16;
    return (unsigned short)u;
}
static __device__ inline float uf(unsigned int u) { return __uint_as_float(u); }

// ---------------------------------------------------------------------------
// Node mask bitmap: bit n = (mask[n] != 0). One u64 per wave via ballot.
__global__ void bitmap_kernel(const int* __restrict__ mask,
                              unsigned long long* __restrict__ bm64) {
    int n = blockIdx.x * blockDim.x + threadIdx.x;
    bool b = (n < NN) && (mask[n] != 0);
    unsigned long long bal = __ballot(b);
    if ((threadIdx.x & 63) == 0) bm64[n >> 6] = bal;
}

// ---------------------------------------------------------------------------
// Counting-sort each CHUNK of edges by coarse bucket (dst>>7) in LDS, then
// flush packed ((dst&127)<<17)|src words into pk[b*BCAP2 ...]. bcnt[b]
// (zeroed) reserves runs AND ends up as the exact per-bucket edge count.
// Scan is wave-level shfl (2 barriers, not 20: at 1-2 blocks/CU barriers
// are expensive).
__global__ __launch_bounds__(NBP) void bucket_scatter(
        const int* __restrict__ srcs, const int* __restrict__ dsts,
        int* __restrict__ bcnt, unsigned int* __restrict__ pk) {
    __shared__ int lh[NBP];
    __shared__ int off[NBP];
    __shared__ int gb[NBP];
    __shared__ int wred[16];
    __shared__ unsigned int ssrc[CHUNK];
    __shared__ unsigned int sdst[CHUNK];
    int t = threadIdx.x;                    // 1024 threads
    int base = blockIdx.x * CHUNK;
    int n = NE - base; if (n > CHUNK) n = CHUNK;

    lh[t] = 0;
    __syncthreads();
    for (int i = t; i < n; i += NBP)
        atomicAdd(&lh[dsts[base + i] >> 7], 1);
    __syncthreads();
    // inclusive scan of lh via wave shfl + 16-partial fold
    int v = lh[t];
    int x = v;
    #pragma unroll
    for (int s = 1; s < 64; s <<= 1) {
        int y = __shfl_up(x, s, 64);
        if ((t & 63) >= s) x += y;
    }
    if ((t & 63) == 63) wred[t >> 6] = x;
    __syncthreads();
    if (t < 16) {
        int ww = wred[t];
        int xx = ww;
        #pragma unroll
        for (int s = 1; s < 16; s <<= 1) {
            int y = __shfl_up(xx, s, 16);
            if (t >= s) xx += y;
        }
        wred[t] = xx - ww;                  // exclusive wave base
    }
    __syncthreads();
    x += wred[t >> 6];                      // inclusive scan value
    int cnt  = v;
    int excl = x - v;
    off[t] = excl;                          // LDS scatter cursor
    if (cnt > 0) gb[t] = t * BCAP2 + atomicAdd(&bcnt[t], cnt) - excl;
    __syncthreads();
    for (int i = t; i < n; i += NBP) {
        int d = dsts[base + i];
        int s = srcs[base + i];
        int p = atomicAdd(&off[d >> 7], 1);
        ssrc[p] = (unsigned int)s;
        sdst[p] = (unsigned int)d;
    }
    __syncthreads();
    for (int p = t; p < n; p += NBP) {
        unsigned int d = sdst[p];
        int b = d >> 7;
        pk[gb[b] + p] = ((d & 127u) << 17) | ssrc[p];
    }
}

// ---------------------------------------------------------------------------
// One block per bucket. 256 sub-buckets: key = local_dst*2 + (src masked?0:1)
// -> per dst: [static(masked-src) | dynamic(unmasked-src)] segments.
// Outputs row_start (static start), mid (dynamic start), dend (end), dinv.
// Fused: Za=bf16(X*dinv) all nodes; masked dsts get static Zb/Y rows once.
// Wave-level scan (2 barriers). Dummy row NN=0.
__global__ void fine_csr(unsigned int* __restrict__ pk,
                         const int* __restrict__ bcnt,
                         const float* __restrict__ X,
                         const unsigned int* __restrict__ bitmap,
                         int* __restrict__ row_start, int* __restrict__ midp,
                         int* __restrict__ dendp,
                         float* __restrict__ dinv,
                         unsigned short* __restrict__ Za,
                         unsigned short* __restrict__ Zb,
                         float* __restrict__ Y) {
    __shared__ int lh[256], off[256];
    __shared__ int wred[4];
    __shared__ float sdi[128];
    __shared__ unsigned int bmp[BMW];
    __shared__ int sbuf[BCAP2];
    int b  = blockIdx.x;
    int t  = threadIdx.x;                   // 256 threads
    int b0 = b * BCAP2;
    int cnt = bcnt[b];
    lh[t] = 0;
    for (int i = t; i < BMW; i += 256) bmp[i] = bitmap[i];
    __syncthreads();
    for (int i = t; i < cnt; i += 256) {
        unsigned int v = pk[b0 + i];
        unsigned int s = v & 0x1FFFFu;
        int mb = (bmp[s >> 5] >> (s & 31)) & 1;
        atomicAdd(&lh[((v >> 17) << 1) | (mb ? 0 : 1)], 1);
    }
    __syncthreads();
    // inclusive scan of lh via wave shfl + 4-partial fold
    int v = lh[t];
    int x = v;
    #pragma unroll
    for (int s = 1; s < 64; s <<= 1) {
        int y = __shfl_up(x, s, 64);
        if ((t & 63) >= s) x += y;
    }
    if ((t & 63) == 63) wred[t >> 6] = x;
    __syncthreads();
    if (t < 4) {
        int ww = wred[t];
        int xx = ww;
        #pragma unroll
        for (int s = 1; s < 4; s <<= 1) {
            int y = __shfl_up(xx, s, 4);
            if (t >= s) xx += y;
        }
        wred[t] = xx - ww;
    }
    __syncthreads();
    x += wred[t >> 6];
    off[t] = x;                             // inclusive scan, stable copy
    int myexcl = x - v;
    __syncthreads();
    if (t < 128) {                          // per-dst outputs
        int cs = lh[2 * t], cd = lh[2 * t + 1];
        int es = off[2 * t] - cs;           // static excl
        int ed = off[2 * t + 1] - cd;       // dynamic excl (= es + cs)
        int c  = cs + cd;
        int dst = (b << 7) + t;
        float di = (c > 0) ? rsqrtf((float)c) : 0.0f;
        sdi[t] = di;
        if (dst < NN) {
            row_start[dst] = b0 + es;
            midp[dst]      = b0 + ed;
            dendp[dst]     = b0 + ed + cd;
            dinv[dst]      = di;
        }
    }
    __syncthreads();
    off[t] = myexcl;                        // becomes the scatter cursor
    __syncthreads();
    for (int i = t; i < cnt; i += 256) {
        unsigned int v2 = pk[b0 + i];
        unsigned int s = v2 & 0x1FFFFu;
        int mb = (bmp[s >> 5] >> (s & 31)) & 1;
        int p = atomicAdd(&off[((v2 >> 17) << 1) | (mb ? 0 : 1)], 1);
        sbuf[p] = (int)s;
    }
    __syncthreads();
    for (int i = t; i < cnt; i += 256)
        pk[b0 + i] = (unsigned int)sbuf[i]; // csr: per dst [static|dynamic]
    // Fused Z0/Y init
    for (int idx = t; idx < 128 * DD; idx += 256) {
        int ldst = idx >> 4;
        int ff   = idx & 15;
        int dst  = (b << 7) + ldst;
        if (dst < NN) {
            float xv = X[dst * DD + ff];
            unsigned short z = f2bf(xv * sdi[ldst]);
            Za[dst * DD + ff] = z;
            if ((bmp[dst >> 5] >> (dst & 31)) & 1) {   // masked: static rows
                Zb[dst * DD + ff] = z;
                Y[dst * DD + ff]  = xv;
            }
        }
    }
    if (b == 0 && t < DD) {                 // dummy zero row (index NN)
        Za[NN * DD + t] = 0;
        Zb[NN * DD + t] = 0;
    }
}

// ---------------------------------------------------------------------------
// Compact the UNMASKED node ids (order arbitrary) via per-wave ballot.
__global__ void compact_kernel(const int* __restrict__ mask,
                               int* __restrict__ ulist, int* __restrict__ ucount) {
    int n = blockIdx.x * blockDim.x + threadIdx.x;
    bool u = (n < NN) && (mask[n] == 0);
    unsigned long long bal = __ballot(u);
    int lane = threadIdx.x & 63;
    int cnt  = __popcll(bal);
    int base = 0;
    if (lane == 0 && cnt > 0) base = atomicAdd(ucount, cnt);
    base = __shfl(base, 0, 64);
    if (u) ulist[base + __popcll(bal & ((1ull << lane) - 1ull))] = n;
}

// ---------------------------------------------------------------------------
// 8-lane-group fold: after 3 steps each lane holds the group-total of
// features {fp, fp+1}, fp = 8*(ln&1) + 4*((ln>>1)&1) + 2*((ln>>2)&1).
static __device__ inline void fold8(float* acc, int ln) {
    {
        int sel = ln & 1;
        #pragma unroll
        for (int k = 0; k < 8; ++k) {
            float mine   = sel ? acc[k + 8] : acc[k];
            float theirs = sel ? acc[k]     : acc[k + 8];
            acc[k] = mine + __shfl_xor(theirs, 1, 8);
        }
    }
    {
        int sel = (ln >> 1) & 1;
        #pragma unroll
        for (int k = 0; k < 4; ++k) {
            float mine   = sel ? acc[k + 4] : acc[k];
            float theirs = sel ? acc[k]     : acc[k + 4];
            acc[k] = mine + __shfl_xor(theirs, 2, 8);
        }
    }
    {
        int sel = (ln >> 2) & 1;
        #pragma unroll
        for (int k = 0; k < 2; ++k) {
            float mine   = sel ? acc[k + 2] : acc[k];
            float theirs = sel ? acc[k]     : acc[k + 2];
            acc[k] = mine + __shfl_xor(theirs, 4, 8);
        }
    }
}

// Accumulate one csr range [lo,hi) into acc[16]; neighbor-per-lane:
// each lane loads a whole 32B bf16 row with 2x dwordx4 (no bpermute).
static __device__ inline void accum_range(const unsigned int* __restrict__ csr,
                                          const unsigned int* __restrict__ Zrow,
                                          int lo, int hi, int ln, float* acc) {
    for (int i = lo; i < hi; i += 8) {
        int p = i + ln;
        int s = (p < hi) ? (int)__builtin_nontemporal_load((const int*)&csr[p]) : NN;
        const uint4* rp = (const uint4*)(Zrow + (size_t)s * 8);
        uint4 r0 = rp[0];
        uint4 r1 = rp[1];
        acc[0]  += uf(r0.x << 16); acc[1]  += uf(r0.x & 0xFFFF0000u);
        acc[2]  += uf(r0.y << 16); acc[3]  += uf(r0.y & 0xFFFF0000u);
        acc[4]  += uf(r0.z << 16); acc[5]  += uf(r0.z & 0xFFFF0000u);
        acc[6]  += uf(r0.w << 16); acc[7]  += uf(r0.w & 0xFFFF0000u);
        acc[8]  += uf(r1.x << 16); acc[9]  += uf(r1.x & 0xFFFF0000u);
        acc[10] += uf(r1.y << 16); acc[11] += uf(r1.y & 0xFFFF0000u);
        acc[12] += uf(r1.z << 16); acc[13] += uf(r1.z & 0xFFFF0000u);
        acc[14] += uf(r1.w << 16); acc[15] += uf(r1.w & 0xFFFF0000u);
    }
}

// ---------------------------------------------------------------------------
// Per-iteration pass. first!=0 (t=0): also accumulate the STATIC range with
// Z0 and emit Sst = GAMMA*dinv*S_static + ALP*X (valid since dynamic srcs use
// the same Z0 at t=0). Else load Sst. v = clip(Sst + GAMMA*dinv*S_dyn);
// last ? Y : Zout = bf16(v*dinv).
__global__ void gather_kernel(const unsigned int* __restrict__ csr,
                              const int* __restrict__ row_start,
                              const int* __restrict__ midp,
                              const int* __restrict__ dendp,
                              const float* __restrict__ dinv,
                              const float* __restrict__ X,
                              float2* __restrict__ Sst2,
                              const int* __restrict__ ulist,
                              const int* __restrict__ ucount,
                              const unsigned int* __restrict__ Zrow,
                              unsigned int* __restrict__ Zout2,
                              float2* __restrict__ Y2,
                              int first, int last) {
    int tid = blockIdx.x * blockDim.x + threadIdx.x;
    int idx = tid >> 3;
    int ln  = tid & 7;
    if (idx >= *ucount) return;
    int node = ulist[idx];
    int mid = midp[node], hi = dendp[node];
    float di = dinv[node];
    int fp = 8 * (ln & 1) + 4 * ((ln >> 1) & 1) + 2 * ((ln >> 2) & 1);

    float s0, s1;
    if (first) {
        int lo = row_start[node];
        float accS[16];
        #pragma unroll
        for (int k = 0; k < 16; ++k) accS[k] = 0.0f;
        accum_range(csr, Zrow, lo, mid, ln, accS);
        fold8(accS, ln);
        float x0 = __builtin_nontemporal_load(&X[node * DD + fp]);
        float x1 = __builtin_nontemporal_load(&X[node * DD + fp + 1]);
        s0 = GAMMA * accS[0] * di + ALP * x0;
        s1 = GAMMA * accS[1] * di + ALP * x1;
        Sst2[node * 8 + (fp >> 1)] = make_float2(s0, s1);
    } else {
        float2 sst = Sst2[node * 8 + (fp >> 1)];
        s0 = sst.x; s1 = sst.y;
    }

    float acc[16];
    #pragma unroll
    for (int k = 0; k < 16; ++k) acc[k] = 0.0f;
    accum_range(csr, Zrow, mid, hi, ln, acc);
    fold8(acc, ln);
    float v0 = s0 + GAMMA * acc[0] * di;
    float v1 = s1 + GAMMA * acc[1] * di;
    v0 = fminf(fmaxf(v0, -1.0f), 1.0f);
    v1 = fminf(fmaxf(v1, -1.0f), 1.0f);
    if (last) {
        Y2[node * 8 + (fp >> 1)] = make_float2(v0, v1);
    } else {
        unsigned int p = (unsigned int)f2bf(v0 * di)
                       | ((unsigned int)f2bf(v1 * di) << 16);
        Zout2[node * 8 + (fp >> 1)] = p;
    }
}

// ---------------------------------------------------------------------------
extern "C" void kernel_launch(void* const* d_in, const int* in_sizes, int n_in,
                              void* d_out, int out_size, void* d_ws, size_t ws_size,
                              hipStream_t stream) {
    const int*   edge_index = (const int*)d_in[0];   // (2, E) int32
    const float* X          = (const float*)d_in[1]; // (N, 16) f32
    const int*   mask       = (const int*)d_in[2];   // (N,) bool as int32

    const int* srcs = edge_index;        // row 0
    const int* dsts = edge_index + NE;   // row 1

    float* Y = (float*)d_out;            // (N, 16) f32 output

    // workspace layout (~30 MB; 16B-aligned Z rows first)
    unsigned short* Za = (unsigned short*)d_ws;              // (NN+1)*DD bf16
    unsigned short* Zb = Za + (NN + 1) * DD;                 // (NN+1)*DD bf16
    float* Sst         = (float*)(Zb + (NN + 1) * DD);       // NN*DD f32
    unsigned int* pk   = (unsigned int*)(Sst + NN * DD);     // NB*BCAP2
    int*   bcnt      = (int*)(pk + NB * BCAP2);              // NBP
    int*   ucount    = bcnt + NBP;                           // 1
    int*   pad       = ucount + 1;                           // 1 (8B align)
    unsigned int* bitmap = (unsigned int*)(pad + 1);         // BMW
    int*   ulist     = (int*)(bitmap + BMW);                 // NN
    int*   midp      = ulist + NN;                           // NN
    int*   dendp     = midp + NN;                            // NN
    int*   row_start = dendp + NN;                           // NN
    float* dinv      = (float*)(row_start + NN);             // NN

    (void)hipMemsetAsync(bcnt, 0, (NBP + 2) * sizeof(int), stream);

    bitmap_kernel<<<(NN + 255) / 256, 256, 0, stream>>>(
        mask, (unsigned long long*)bitmap);
    bucket_scatter<<<NCHUNK, NBP, 0, stream>>>(srcs, dsts, bcnt, pk);
    fine_csr<<<NB, 256, 0, stream>>>(pk, bcnt, X, bitmap, row_start, midp, dendp,
                                     dinv, Za, Zb, Y);
    compact_kernel<<<(NN + 255) / 256, 256, 0, stream>>>(mask, ulist, ucount);

    // Z ping-pong: Za -> Zb -> Za -> Zb -> Za -> Y(last)
    const unsigned short* zin  = Za;
    unsigned short*       zout = Zb;
    for (int t = 0; t < 5; ++t) {
        int first = (t == 0);
        int last  = (t == 4);
        gather_kernel<<<(NN * 8) / 256, 256, 0, stream>>>(
            pk, row_start, midp, dendp, dinv, X, (float2*)Sst, ulist, ucount,
            (const unsigned int*)zin, (unsigned int*)zout, (float2*)Y,
            first, last);
        const unsigned short* tmp = zout;
        zout = (unsigned short*)zin;
        zin  = tmp;
    }
}